// Round 1
// baseline (213.040 us; speedup 1.0000x reference)
//
#include <hip/hip_runtime.h>
#include <stdint.h>

// Problem dims
#define BB   64
#define TSEQ 128
#define ISEQ 197
#define DD   768
#define TM   127   // text tokens used (drop token 0)
#define IM   196   // image tokens used (drop token 0)
#define NK   24    // 768 / 32
#define A_KB (TM*64)   // bytes per K-step block of one text matrix (127 rows x 64B)
#define B_KB (IM*64)   // bytes per K-step block of one image matrix

typedef float    f32x4 __attribute__((ext_vector_type(4)));
typedef _Float16 h8    __attribute__((ext_vector_type(8)));
typedef _Float16 h4    __attribute__((ext_vector_type(4)));
typedef float    fvec4 __attribute__((ext_vector_type(4)));

// monotonic float<->uint mapping for atomicMax-based float max
__device__ __forceinline__ unsigned fkey(float f){
  unsigned u = __float_as_uint(f);
  return (u & 0x80000000u) ? ~u : (u | 0x80000000u);
}
__device__ __forceinline__ float fdekey(unsigned k){
  unsigned u = (k & 0x80000000u) ? (k & 0x7fffffffu) : ~k;
  return __uint_as_float(u);
}
__device__ __forceinline__ float waveSum(float v){
  #pragma unroll
  for (int s = 1; s < 64; s <<= 1) v += __shfl_xor(v, s, 64);
  return v;
}

// ---------------------------------------------------------------------------
// Mask prep: replicate _mask_eos + drop t=0. Per b: valid[t'] (t'=0..126),
// bias (0 valid / -3e38 invalid, row 127 invalid), sel (1/0), count.
__global__ void mask_kernel(const int* __restrict__ pmG, float* __restrict__ bias,
                            float* __restrict__ sel, int* __restrict__ cnt)
{
  int b = blockIdx.x; int l = threadIdx.x;          // 64 threads
  const int* row = pmG + b*TSEQ;
  int p0 = row[l]; int p1 = row[l+64];
  unsigned long long m0 = __ballot(p0 == 0);
  unsigned long long m1 = __ballot(p1 == 0);
  int lz = 0;
  if (m1)      lz = 64 + (63 - __clzll(m1));        // last zero index = eos
  else if (m0) lz = 63 - __clzll(m0);
  // t' = l  -> t = l+1
  int t1 = l + 1;
  int q1 = row[t1];
  bool v1 = (q1 == 0) && (t1 != lz);
  // t' = l+64 -> t = l+65 (t'=127 i.e. padded GEMM row stays invalid)
  int t2 = l + 65;
  bool v2 = false;
  if (t2 < TSEQ){ int q2 = row[t2]; v2 = (q2 == 0) && (t2 != lz); }
  bias[b*128 + l]      = v1 ? 0.f : -3.0e38f;
  sel [b*128 + l]      = v1 ? 1.f : 0.f;
  bias[b*128 + 64 + l] = v2 ? 0.f : -3.0e38f;
  sel [b*128 + 64 + l] = v2 ? 1.f : 0.f;
  unsigned long long vm1 = __ballot(v1);
  unsigned long long vm2 = __ballot(v2);
  if (l == 0) cnt[b] = __popcll(vm1) + __popcll(vm2);
}

// ---------------------------------------------------------------------------
// f32 -> fp16 conversion into K-blocked layout: [b][ks][token][32 halves]
// so the GEMM's per-K-step staging reads are fully contiguous.
__global__ void cvt_txt_kernel(const float* __restrict__ src, _Float16* __restrict__ dst){
  int t = blockIdx.x;   // 0..126
  int b = blockIdx.y;
  int i = threadIdx.x;  // 0..191 (192 = 768/4)
  const fvec4* s = (const fvec4*)(src + ((size_t)b*TSEQ + t + 1)*DD) + i;
  fvec4 v = *s;
  h4 h; h.x=(_Float16)v.x; h.y=(_Float16)v.y; h.z=(_Float16)v.z; h.w=(_Float16)v.w;
  int ks = i >> 3; int o = (i & 7)*4;
  _Float16* d = dst + (size_t)b*(NK*TM*32) + (size_t)ks*(TM*32) + t*32 + o;
  *(h4*)d = h;
}
__global__ void cvt_img_kernel(const float* __restrict__ src, _Float16* __restrict__ dst){
  int t = blockIdx.x;   // 0..195
  int b = blockIdx.y;
  int i = threadIdx.x;
  const fvec4* s = (const fvec4*)(src + ((size_t)b*ISEQ + t + 1)*DD) + i;
  fvec4 v = *s;
  h4 h; h.x=(_Float16)v.x; h.y=(_Float16)v.y; h.z=(_Float16)v.z; h.w=(_Float16)v.w;
  int ks = i >> 3; int o = (i & 7)*4;
  _Float16* d = dst + (size_t)b*(NK*IM*32) + (size_t)ks*(IM*32) + t*32 + o;
  *(h4*)d = h;
}

// ---------------------------------------------------------------------------
// Main: one workgroup per (bx=text, by=image) pair.
// GEMM 128(M,pad127) x 224(N,pad196) x 768 via mfma_f32_16x16x32_f16,
// 4 waves in 2Mx2N grid, wave tile 4x7 16x16 tiles. Double-buffered LDS,
// reg-staged, XOR-swizzled 16B granules (pg = g ^ ((r>>1)&3)) so frag
// ds_read_b128 is <=2-way bank conflict (free). Fused row/col max.
__global__ __launch_bounds__(256, 2)
void cmli_pair_kernel(const _Float16* __restrict__ txtH,
                      const _Float16* __restrict__ imgH,
                      const float* __restrict__ biasG,
                      const float* __restrict__ selG,
                      const int* __restrict__ cntG,
                      const float* __restrict__ scaleP,
                      float* __restrict__ out)
{
  // LDS: A0 8192 | B0 14336 | A1 8192 | B1 14336 | rowKeys 512 | colKeys 896 | parts 64
  __shared__ __align__(16) char smem[45056 + 512 + 896 + 64];
  unsigned* rowKeys = (unsigned*)(smem + 45056);
  unsigned* colKeys = (unsigned*)(smem + 45056 + 512);
  float*    parts   = (float*)(smem + 45056 + 512 + 896);

  const int tid  = threadIdx.x;
  const int lane = tid & 63;
  const int w    = tid >> 6;
  const int wm   = w & 1;      // M half (0..1)
  const int wn   = w >> 1;     // N half (0..1)
  const int bx   = blockIdx.x >> 6;   // text index
  const int by   = blockIdx.x & 63;   // image index

  const char* tA = (const char*)txtH + (size_t)bx * (NK*A_KB);
  const char* tB = (const char*)imgH + (size_t)by * (NK*B_KB);

  // fragment read offsets (swizzle is lane-constant: pg = g ^ ((r>>1)&3))
  const int pg   = (lane>>4) ^ ((lane>>1)&3);
  const int aOff = (wm*64  + (lane&15))*64 + pg*16;   // + mt*1024
  const int bOff = (wn*112 + (lane&15))*64 + pg*16;   // + nt*1024

  // staging: thread covers 16B chunk c; phys (r=c>>2, pg=c&3) <- logical g
  int sA[2], dA[2], sB[4], dB[4];
  #pragma unroll
  for (int i=0;i<2;i++){
    int c = tid + 256*i; int r = c>>2; int p = c&3; int g = p ^ ((r>>1)&3);
    sA[i] = min(r,126)*64 + g*16; dA[i] = c*16;
  }
  #pragma unroll
  for (int i=0;i<4;i++){
    int c = tid + 256*i; int r = c>>2; int p = c&3; int g = p ^ ((r>>1)&3);
    sB[i] = min(r,195)*64 + g*16; dB[i] = c*16;
  }
  const bool hasB3 = (tid < 128);   // 896 B-chunks: 3.5 passes of 256

  f32x4 acc[4][7];
  #pragma unroll
  for (int m=0;m<4;m++)
    #pragma unroll
    for (int n=0;n<7;n++)
      acc[m][n] = (f32x4){0.f,0.f,0.f,0.f};

  if (tid < 128) rowKeys[tid] = 0u;   // key 0 < key(any finite float)
  if (tid < 224) colKeys[tid] = 0u;

  // prologue: stage ks=0 into buf0
  {
    uint4 va0 = *(const uint4*)(tA + sA[0]);
    uint4 va1 = *(const uint4*)(tA + sA[1]);
    uint4 vb0 = *(const uint4*)(tB + sB[0]);
    uint4 vb1 = *(const uint4*)(tB + sB[1]);
    uint4 vb2 = *(const uint4*)(tB + sB[2]);
    uint4 vb3;
    if (hasB3) vb3 = *(const uint4*)(tB + sB[3]);
    char* A0 = smem; char* B0 = smem + 8192;
    *(uint4*)(A0 + dA[0]) = va0;
    *(uint4*)(A0 + dA[1]) = va1;
    *(uint4*)(B0 + dB[0]) = vb0;
    *(uint4*)(B0 + dB[1]) = vb1;
    *(uint4*)(B0 + dB[2]) = vb2;
    if (hasB3) *(uint4*)(B0 + dB[3]) = vb3;
  }
  __syncthreads();

  for (int ks=0; ks<NK; ks++){
    const int cur = ks & 1;
    uint4 va0,va1,vb0,vb1,vb2,vb3;
    if (ks+1 < NK){                   // issue next-tile loads early (latency hides under MFMA)
      const char* at = tA + (size_t)(ks+1)*A_KB;
      const char* bt = tB + (size_t)(ks+1)*B_KB;
      va0 = *(const uint4*)(at + sA[0]);
      va1 = *(const uint4*)(at + sA[1]);
      vb0 = *(const uint4*)(bt + sB[0]);
      vb1 = *(const uint4*)(bt + sB[1]);
      vb2 = *(const uint4*)(bt + sB[2]);
      if (hasB3) vb3 = *(const uint4*)(bt + sB[3]);
    }
    const char* Ab = smem + (cur ? 22528 : 0);
    const char* Bb = smem + (cur ? 30720 : 8192);
    h8 af[4]; h8 bf[7];
    #pragma unroll
    for (int m=0;m<4;m++) af[m] = *(const h8*)(Ab + aOff + m*1024);
    #pragma unroll
    for (int n=0;n<7;n++) bf[n] = *(const h8*)(Bb + bOff + n*1024);
    #pragma unroll
    for (int m=0;m<4;m++)
      #pragma unroll
      for (int n=0;n<7;n++)
        acc[m][n] = __builtin_amdgcn_mfma_f32_16x16x32_f16(af[m], bf[n], acc[m][n], 0,0,0);
    if (ks+1 < NK){                   // write next tile into the other buffer
      char* An = smem + (cur ? 0 : 22528);
      char* Bn = smem + (cur ? 8192 : 30720);
      *(uint4*)(An + dA[0]) = va0;
      *(uint4*)(An + dA[1]) = va1;
      *(uint4*)(Bn + dB[0]) = vb0;
      *(uint4*)(Bn + dB[1]) = vb1;
      *(uint4*)(Bn + dB[2]) = vb2;
      if (hasB3) *(uint4*)(Bn + dB[3]) = vb3;
    }
    __syncthreads();
  }

  // --- fused reductions ---
  const float scale = scaleP[0];
  #pragma unroll
  for (int m=0;m<4;m++)
    #pragma unroll
    for (int n=0;n<7;n++)
      acc[m][n] *= scale;

  // rowmax (t2i path): max over all cols; C/D map: row=(lane>>4)*4+j, col=lane&15
  #pragma unroll
  for (int m=0;m<4;m++){
    f32x4 r = acc[m][0];
    #pragma unroll
    for (int n=1;n<7;n++){
      r.x = fmaxf(r.x, acc[m][n].x); r.y = fmaxf(r.y, acc[m][n].y);
      r.z = fmaxf(r.z, acc[m][n].z); r.w = fmaxf(r.w, acc[m][n].w);
    }
    #pragma unroll
    for (int s=1;s<16;s<<=1){
      r.x = fmaxf(r.x, __shfl_xor(r.x, s, 64));
      r.y = fmaxf(r.y, __shfl_xor(r.y, s, 64));
      r.z = fmaxf(r.z, __shfl_xor(r.z, s, 64));
      r.w = fmaxf(r.w, __shfl_xor(r.w, s, 64));
    }
    if ((lane & 15) == 0){
      int row = wm*64 + m*16 + (lane>>4)*4;
      atomicMax(&rowKeys[row+0], fkey(r.x));
      atomicMax(&rowKeys[row+1], fkey(r.y));
      atomicMax(&rowKeys[row+2], fkey(r.z));
      atomicMax(&rowKeys[row+3], fkey(r.w));
    }
  }

  // colmax (i2t path): max over valid rows (bias = 0 valid / -3e38 masked)
  fvec4 bv[4];
  #pragma unroll
  for (int m=0;m<4;m++)
    bv[m] = *(const fvec4*)(biasG + bx*128 + wm*64 + m*16 + (lane>>4)*4);
  #pragma unroll
  for (int n=0;n<7;n++){
    float c = -3.0e38f;
    #pragma unroll
    for (int m=0;m<4;m++){
      c = fmaxf(c, acc[m][n].x + bv[m].x);
      c = fmaxf(c, acc[m][n].y + bv[m].y);
      c = fmaxf(c, acc[m][n].z + bv[m].z);
      c = fmaxf(c, acc[m][n].w + bv[m].w);
    }
    c = fmaxf(c, __shfl_xor(c, 16, 64));
    c = fmaxf(c, __shfl_xor(c, 32, 64));
    if (lane < 16){
      int col = wn*112 + n*16 + lane;
      atomicMax(&colKeys[col], fkey(c));
    }
  }
  __syncthreads();

  // finalize pair outputs
  float v = 0.f;
  if (tid < 128){
    float s = selG[bx*128 + tid];
    v = (s > 0.5f) ? fdekey(rowKeys[tid]) : 0.f;
  }
  float u = (tid < IM) ? fdekey(colKeys[tid]) : 0.f;
  v = waveSum(v); u = waveSum(u);
  if (lane == 0){ parts[w] = v; parts[4+w] = u; }
  __syncthreads();
  if (tid == 0){
    float numer = parts[0]+parts[1]+parts[2]+parts[3];
    float csum  = parts[4]+parts[5]+parts[6]+parts[7];
    float denom = fmaxf((float)cntG[bx], 1e-6f);
    out[1 + 4096 + blockIdx.x] = numer / denom;        // t2i[x][y]
    out[1 + blockIdx.x]        = csum * (1.f/196.f);   // i2t[x][y]
  }
}

// ---------------------------------------------------------------------------
// Loss: wave0 = i2t CE, wave1 = t2i CE; loss = mean of the two diag-CE means.
__global__ void loss_kernel(float* __restrict__ out){
  __shared__ float p[2];
  int w = threadIdx.x >> 6, lane = threadIdx.x & 63;
  const float* M = out + 1 + w*4096;
  const float* r = M + lane*64;
  float mx = -3.0e38f;
  for (int j=0;j<64;j++) mx = fmaxf(mx, r[j]);
  float se = 0.f;
  for (int j=0;j<64;j++) se += __expf(r[j]-mx);
  float nll = (mx + __logf(se)) - r[lane];
  float s = waveSum(nll);
  if (lane == 0) p[w] = s;
  __syncthreads();
  if (threadIdx.x == 0) out[0] = (p[0] + p[1]) * (0.5f/64.f);
}

// ---------------------------------------------------------------------------
extern "C" void kernel_launch(void* const* d_in, const int* in_sizes, int n_in,
                              void* d_out, int out_size, void* d_ws, size_t ws_size,
                              hipStream_t stream)
{
  const float* imgF   = (const float*)d_in[0];  // (64,197,768) f32
  const float* txtF   = (const float*)d_in[1];  // (64,128,768) f32
  const int*   pm     = (const int*)d_in[2];    // (64,128) i32
  const float* scaleP = (const float*)d_in[3];  // (1,) f32
  float* out = (float*)d_out;                   // [loss(1) | i2t(4096) | t2i(4096)]

  // workspace carve (needs ~30.4 MB)
  char* ws = (char*)d_ws;
  _Float16* txtH = (_Float16*)ws;                        // 12,484,608 B
  _Float16* imgH = (_Float16*)(ws + 12484608);           // 19,267,584 B
  float* bias = (float*)(ws + 31752192);                 // 32 KB
  float* sel  = (float*)(ws + 31784960);                 // 32 KB
  int*   cnt  = (int*)(ws + 31817728);                   // 256 B

  hipLaunchKernelGGL(mask_kernel,    dim3(BB),      dim3(64),  0, stream, pm, bias, sel, cnt);
  hipLaunchKernelGGL(cvt_txt_kernel, dim3(TM, BB),  dim3(192), 0, stream, txtF, txtH);
  hipLaunchKernelGGL(cvt_img_kernel, dim3(IM, BB),  dim3(192), 0, stream, imgF, imgH);
  hipLaunchKernelGGL(cmli_pair_kernel, dim3(BB*BB), dim3(256), 0, stream,
                     txtH, imgH, bias, sel, cnt, scaleP, out);
  hipLaunchKernelGGL(loss_kernel,    dim3(1),       dim3(128), 0, stream, out);
}

// Round 2
// 201.221 us; speedup vs baseline: 1.0587x; 1.0587x over previous
//
#include <hip/hip_runtime.h>
#include <stdint.h>

// Problem dims
#define BB   64
#define TSEQ 128
#define ISEQ 197
#define DD   768
#define TM   127   // text tokens used (drop token 0)
#define IM   196   // image tokens used (drop token 0)
#define NK   24    // 768 / 32
#define A_KB (TM*64)   // bytes per K-step block of one text matrix (127 rows x 64B)
#define B_KB (IM*64)   // bytes per K-step block of one image matrix

// LDS map (bytes): A dbuf 2x8192 | B tbuf 3x14336 | rowKeys 512 | colKeys 896 | parts 64
#define LDS_B0   16384
#define LDS_RK   59392
#define LDS_CK   59904
#define LDS_PT   60800
#define LDS_TOT  60864

typedef float    f32x4 __attribute__((ext_vector_type(4)));
typedef _Float16 h8    __attribute__((ext_vector_type(8)));
typedef _Float16 h4    __attribute__((ext_vector_type(4)));
typedef float    fvec4 __attribute__((ext_vector_type(4)));

// monotonic float<->uint mapping for atomicMax-based float max
__device__ __forceinline__ unsigned fkey(float f){
  unsigned u = __float_as_uint(f);
  return (u & 0x80000000u) ? ~u : (u | 0x80000000u);
}
__device__ __forceinline__ float fdekey(unsigned k){
  unsigned u = (k & 0x80000000u) ? (k & 0x7fffffffu) : ~k;
  return __uint_as_float(u);
}
__device__ __forceinline__ float waveSum(float v){
  #pragma unroll
  for (int s = 1; s < 64; s <<= 1) v += __shfl_xor(v, s, 64);
  return v;
}

// async global->LDS, 16B per lane, wave-uniform LDS base (m104), per-lane global src (m173)
__device__ __forceinline__ void gload_lds16(const void* g, void* l){
  __builtin_amdgcn_global_load_lds(
      (const __attribute__((address_space(1))) void*)g,
      (__attribute__((address_space(3))) void*)l, 16, 0, 0);
}

// ---------------------------------------------------------------------------
// Mask prep: replicate _mask_eos + drop t=0. Valid text rows are the
// contiguous prefix [0, len-2); cnt = len-2.
__global__ void mask_kernel(const int* __restrict__ pmG, float* __restrict__ bias,
                            float* __restrict__ sel, int* __restrict__ cnt)
{
  int b = blockIdx.x; int l = threadIdx.x;          // 64 threads
  const int* row = pmG + b*TSEQ;
  int p0 = row[l]; int p1 = row[l+64];
  unsigned long long m0 = __ballot(p0 == 0);
  unsigned long long m1 = __ballot(p1 == 0);
  int lz = 0;
  if (m1)      lz = 64 + (63 - __clzll(m1));        // last zero index = eos
  else if (m0) lz = 63 - __clzll(m0);
  int t1 = l + 1;
  int q1 = row[t1];
  bool v1 = (q1 == 0) && (t1 != lz);
  int t2 = l + 65;
  bool v2 = false;
  if (t2 < TSEQ){ int q2 = row[t2]; v2 = (q2 == 0) && (t2 != lz); }
  bias[b*128 + l]      = v1 ? 0.f : -3.0e38f;
  sel [b*128 + l]      = v1 ? 1.f : 0.f;
  bias[b*128 + 64 + l] = v2 ? 0.f : -3.0e38f;
  sel [b*128 + 64 + l] = v2 ? 1.f : 0.f;
  unsigned long long vm1 = __ballot(v1);
  unsigned long long vm2 = __ballot(v2);
  if (l == 0) cnt[b] = __popcll(vm1) + __popcll(vm2);
}

// ---------------------------------------------------------------------------
// f32 -> fp16 conversion into K-blocked layout: [b][ks][token][32 halves]
__global__ void cvt_txt_kernel(const float* __restrict__ src, _Float16* __restrict__ dst){
  int t = blockIdx.x;   // 0..126
  int b = blockIdx.y;
  int i = threadIdx.x;  // 0..191
  const fvec4* s = (const fvec4*)(src + ((size_t)b*TSEQ + t + 1)*DD) + i;
  fvec4 v = *s;
  h4 h; h.x=(_Float16)v.x; h.y=(_Float16)v.y; h.z=(_Float16)v.z; h.w=(_Float16)v.w;
  int ks = i >> 3; int o = (i & 7)*4;
  _Float16* d = dst + (size_t)b*(NK*TM*32) + (size_t)ks*(TM*32) + t*32 + o;
  *(h4*)d = h;
}
__global__ void cvt_img_kernel(const float* __restrict__ src, _Float16* __restrict__ dst){
  int t = blockIdx.x;   // 0..195
  int b = blockIdx.y;
  int i = threadIdx.x;
  const fvec4* s = (const fvec4*)(src + ((size_t)b*ISEQ + t + 1)*DD) + i;
  fvec4 v = *s;
  h4 h; h.x=(_Float16)v.x; h.y=(_Float16)v.y; h.z=(_Float16)v.z; h.w=(_Float16)v.w;
  int ks = i >> 3; int o = (i & 7)*4;
  _Float16* d = dst + (size_t)b*(NK*IM*32) + (size_t)ks*(IM*32) + t*32 + o;
  *(h4*)d = h;
}

// ---------------------------------------------------------------------------
// Main: one workgroup per (bx=text, by=image) pair.
// 128x224x768 f16 MFMA GEMM; counted-vmcnt global_load_lds pipeline:
// A double-buffered (depth 2), B triple-buffered (depth 3); raw s_barrier,
// vmcnt never drained to 0 in the loop. Dynamic-M: m-tiles g >= mtc skipped
// (interleaved g = wm + 2j across the two M-waves for balance).
__global__ __launch_bounds__(256, 2)
void cmli_pair_kernel(const _Float16* __restrict__ txtH,
                      const _Float16* __restrict__ imgH,
                      const float* __restrict__ biasG,
                      const float* __restrict__ selG,
                      const int* __restrict__ cntG,
                      const float* __restrict__ scaleP,
                      float* __restrict__ out)
{
  __shared__ __align__(16) char smem[LDS_TOT];
  unsigned* rowKeys = (unsigned*)(smem + LDS_RK);
  unsigned* colKeys = (unsigned*)(smem + LDS_CK);
  float*    parts   = (float*)(smem + LDS_PT);

  const int tid  = threadIdx.x;
  const int lane = tid & 63;
  const int w    = tid >> 6;
  const int wm   = w & 1;      // M interleave class
  const int wn   = w >> 1;     // N half (0..1)
  const int bx   = blockIdx.x >> 6;   // text index
  const int by   = blockIdx.x & 63;   // image index

  const char* tA = (const char*)txtH + (size_t)bx * (NK*A_KB);
  const char* tB = (const char*)imgH + (size_t)by * (NK*B_KB);
  const int mtc = (cntG[bx] + 15) >> 4;   // active m-tiles, 4..8

  // --- staging tables (source pre-swizzled so linear LDS dest = swizzled layout) ---
  // A: 8 chunks of 1024B over 4 waves (2 each); B: 14 chunks (4,4,3,3)
  int aSrc[2], aLds[2];
  #pragma unroll
  for (int i=0;i<2;i++){
    int c = w + 4*i; int p = c*64 + lane; int r = p>>2; int pg = p&3;
    int g = pg ^ ((r>>1)&3);
    aSrc[i] = min(r,126)*64 + g*16; aLds[i] = c*1024;
  }
  const int kB = (w < 2) ? 4 : 3;
  int bSrc[4], bLds[4];
  #pragma unroll
  for (int i=0;i<4;i++){
    int c = w + 4*i; if (c > 13) c = 13;
    int p = c*64 + lane; int r = p>>2; int pg = p&3;
    int g = pg ^ ((r>>1)&3);
    bSrc[i] = min(r,195)*64 + g*16; bLds[i] = c*1024;
  }

  // fragment read offsets (swizzle-consistent: pg = (lane>>4) ^ ((lane>>1)&3))
  const int pgf  = (lane>>4) ^ ((lane>>1)&3);
  const int aOff = (lane&15)*64 + pgf*16;              // + g*1024 + abuf*8192
  const int bOff = (wn*112 + (lane&15))*64 + pgf*16;   // + n*1024 + Bbase

  f32x4 acc[4][7];
  #pragma unroll
  for (int j=0;j<4;j++)
    #pragma unroll
    for (int n=0;n<7;n++)
      acc[j][n] = (f32x4){0.f,0.f,0.f,0.f};

  if (tid < 128) rowKeys[tid] = 0u;
  if (tid < 224) colKeys[tid] = 0u;

  // --- prologue: B(0)->b0, A(0)->a0, B(1)->b1; wait so only B(1) may be in flight ---
  {
    #pragma unroll
    for (int i=0;i<4;i++) if (i < kB) gload_lds16(tB + bSrc[i], smem + LDS_B0 + bLds[i]);
    #pragma unroll
    for (int i=0;i<2;i++) gload_lds16(tA + aSrc[i], smem + aLds[i]);
    const char* bt1 = tB + B_KB;
    #pragma unroll
    for (int i=0;i<4;i++) if (i < kB) gload_lds16(bt1 + bSrc[i], smem + LDS_B0 + 14336 + bLds[i]);
    if (w < 2) asm volatile("s_waitcnt vmcnt(4)" ::: "memory");
    else       asm volatile("s_waitcnt vmcnt(3)" ::: "memory");
    __builtin_amdgcn_s_barrier();
    asm volatile("" ::: "memory");
  }

  int rbA = 0, rbB = 0;
  for (int t=0; t<NK; t++){
    // issue A(t+1) then B(t+2) (clamped; redundant tail loads land in dead buffers)
    {
      int ka  = (t+1 < NK) ? t+1 : NK-1;
      int kb2 = (t+2 < NK) ? t+2 : NK-1;
      const char* at = tA + (size_t)ka  * A_KB;
      const char* bt = tB + (size_t)kb2 * B_KB;
      int aBase = (rbA ^ 1) * 8192;
      int sb3 = rbB + 2; if (sb3 >= 3) sb3 -= 3;
      int bBase = LDS_B0 + sb3 * 14336;
      #pragma unroll
      for (int i=0;i<2;i++) gload_lds16(at + aSrc[i], smem + aBase + aLds[i]);
      #pragma unroll
      for (int i=0;i<4;i++) if (i < kB) gload_lds16(bt + bSrc[i], smem + bBase + bLds[i]);
    }
    // compute on tile t
    const char* Ab = smem + rbA*8192;
    const char* Bb = smem + LDS_B0 + rbB*14336;
    h8 af[4]; h8 bf[7];
    #pragma unroll
    for (int n=0;n<7;n++) bf[n] = *(const h8*)(Bb + bOff + n*1024);
    #pragma unroll
    for (int j=0;j<4;j++){
      int g = wm + 2*j;
      if (g < mtc) af[j] = *(const h8*)(Ab + aOff + g*1024);
    }
    #pragma unroll
    for (int j=0;j<4;j++){
      int g = wm + 2*j;
      if (g < mtc){
        #pragma unroll
        for (int n=0;n<7;n++)
          acc[j][n] = __builtin_amdgcn_mfma_f32_16x16x32_f16(af[j], bf[n], acc[j][n], 0,0,0);
      }
    }
    // counted wait: A(t+1) and B(t+1) done; B(t+2) may stay in flight
    if (w < 2) asm volatile("s_waitcnt vmcnt(4)" ::: "memory");
    else       asm volatile("s_waitcnt vmcnt(3)" ::: "memory");
    __builtin_amdgcn_s_barrier();
    asm volatile("" ::: "memory");
    rbA ^= 1; rbB = (rbB == 2) ? 0 : rbB + 1;
  }

  // --- fused reductions ---
  const float scale = scaleP[0];
  #pragma unroll
  for (int j=0;j<4;j++){
    int g = wm + 2*j;
    if (g < mtc){
      #pragma unroll
      for (int n=0;n<7;n++) acc[j][n] *= scale;
    }
  }

  // rowmax (t2i path); C/D map: row=(lane>>4)*4+q, col=lane&15
  #pragma unroll
  for (int j=0;j<4;j++){
    int g = wm + 2*j;
    if (g < mtc){
      f32x4 r = acc[j][0];
      #pragma unroll
      for (int n=1;n<7;n++){
        r.x = fmaxf(r.x, acc[j][n].x); r.y = fmaxf(r.y, acc[j][n].y);
        r.z = fmaxf(r.z, acc[j][n].z); r.w = fmaxf(r.w, acc[j][n].w);
      }
      #pragma unroll
      for (int s=1;s<16;s<<=1){
        r.x = fmaxf(r.x, __shfl_xor(r.x, s, 64));
        r.y = fmaxf(r.y, __shfl_xor(r.y, s, 64));
        r.z = fmaxf(r.z, __shfl_xor(r.z, s, 64));
        r.w = fmaxf(r.w, __shfl_xor(r.w, s, 64));
      }
      if ((lane & 15) == 0){
        int row = g*16 + (lane>>4)*4;
        atomicMax(&rowKeys[row+0], fkey(r.x));
        atomicMax(&rowKeys[row+1], fkey(r.y));
        atomicMax(&rowKeys[row+2], fkey(r.z));
        atomicMax(&rowKeys[row+3], fkey(r.w));
      }
    }
  }

  // colmax (i2t path): max over valid rows (bias = 0 valid / -3e38 masked)
  fvec4 bv[4];
  #pragma unroll
  for (int j=0;j<4;j++){
    int g = wm + 2*j;
    if (g < mtc)
      bv[j] = *(const fvec4*)(biasG + bx*128 + g*16 + (lane>>4)*4);
  }
  #pragma unroll
  for (int n=0;n<7;n++){
    float c = -3.0e38f;
    #pragma unroll
    for (int j=0;j<4;j++){
      int g = wm + 2*j;
      if (g < mtc){
        c = fmaxf(c, acc[j][n].x + bv[j].x);
        c = fmaxf(c, acc[j][n].y + bv[j].y);
        c = fmaxf(c, acc[j][n].z + bv[j].z);
        c = fmaxf(c, acc[j][n].w + bv[j].w);
      }
    }
    c = fmaxf(c, __shfl_xor(c, 16, 64));
    c = fmaxf(c, __shfl_xor(c, 32, 64));
    if (lane < 16){
      int col = wn*112 + n*16 + lane;
      atomicMax(&colKeys[col], fkey(c));
    }
  }
  __syncthreads();

  // finalize pair outputs
  float v = 0.f;
  if (tid < 128){
    float s = selG[bx*128 + tid];
    v = (s > 0.5f) ? fdekey(rowKeys[tid]) : 0.f;
  }
  float u = (tid < IM) ? fdekey(colKeys[tid]) : 0.f;
  v = waveSum(v); u = waveSum(u);
  if (lane == 0){ parts[w] = v; parts[4+w] = u; }
  __syncthreads();
  if (tid == 0){
    float numer = parts[0]+parts[1]+parts[2]+parts[3];
    float csum  = parts[4]+parts[5]+parts[6]+parts[7];
    float denom = fmaxf((float)cntG[bx], 1e-6f);
    out[1 + 4096 + blockIdx.x] = numer / denom;        // t2i[x][y]
    out[1 + blockIdx.x]        = csum * (1.f/196.f);   // i2t[x][y]
  }
}

// ---------------------------------------------------------------------------
// Loss: wave0 = i2t CE, wave1 = t2i CE; loss = mean of the two diag-CE means.
__global__ void loss_kernel(float* __restrict__ out){
  __shared__ float p[2];
  int w = threadIdx.x >> 6, lane = threadIdx.x & 63;
  const float* M = out + 1 + w*4096;
  const float* r = M + lane*64;
  float mx = -3.0e38f;
  for (int j=0;j<64;j++) mx = fmaxf(mx, r[j]);
  float se = 0.f;
  for (int j=0;j<64;j++) se += __expf(r[j]-mx);
  float nll = (mx + __logf(se)) - r[lane];
  float s = waveSum(nll);
  if (lane == 0) p[w] = s;
  __syncthreads();
  if (threadIdx.x == 0) out[0] = (p[0] + p[1]) * (0.5f/64.f);
}

// ---------------------------------------------------------------------------
extern "C" void kernel_launch(void* const* d_in, const int* in_sizes, int n_in,
                              void* d_out, int out_size, void* d_ws, size_t ws_size,
                              hipStream_t stream)
{
  const float* imgF   = (const float*)d_in[0];  // (64,197,768) f32
  const float* txtF   = (const float*)d_in[1];  // (64,128,768) f32
  const int*   pm     = (const int*)d_in[2];    // (64,128) i32
  const float* scaleP = (const float*)d_in[3];  // (1,) f32
  float* out = (float*)d_out;                   // [loss(1) | i2t(4096) | t2i(4096)]

  char* ws = (char*)d_ws;
  _Float16* txtH = (_Float16*)ws;                        // 12,484,608 B
  _Float16* imgH = (_Float16*)(ws + 12484608);           // 19,267,584 B
  float* bias = (float*)(ws + 31752192);                 // 32 KB
  float* sel  = (float*)(ws + 31784960);                 // 32 KB
  int*   cnt  = (int*)(ws + 31817728);                   // 256 B

  hipLaunchKernelGGL(mask_kernel,    dim3(BB),      dim3(64),  0, stream, pm, bias, sel, cnt);
  hipLaunchKernelGGL(cvt_txt_kernel, dim3(TM, BB),  dim3(192), 0, stream, txtF, txtH);
  hipLaunchKernelGGL(cvt_img_kernel, dim3(IM, BB),  dim3(192), 0, stream, imgF, imgH);
  hipLaunchKernelGGL(cmli_pair_kernel, dim3(BB*BB), dim3(256), 0, stream,
                     txtH, imgH, bias, sel, cnt, scaleP, out);
  hipLaunchKernelGGL(loss_kernel,    dim3(1),       dim3(128), 0, stream, out);
}